// Round 13
// baseline (691.083 us; speedup 1.0000x reference)
//
#include <hip/hip_runtime.h>
#include <stdint.h>

typedef __attribute__((ext_vector_type(8))) short short8;
typedef __attribute__((ext_vector_type(4))) float f32x4;
typedef __attribute__((ext_vector_type(2))) unsigned int u32x2;
typedef unsigned short u16;
typedef unsigned int u32;

#define NPER 6
// frag-major weight regions (bf16 element offsets). Each frag = 512 elems = 1KB,
// lane-major: frag[lane][j] = W[n(frag,lane)][k(frag,lane,j)].   (identical to R10/R11)
#define SA_F   0
#define CRW_F  131072
#define CW1_F  196608
#define CW2_F  262144
#define TRW_F  266240
#define TW1_F  331776
#define TW2_F  397312
#define WS_WELE 401408   // h16 follows

__device__ inline u16 f2b(float f){                 // f32 -> bf16 (RNE) -- host-side converters only
  u32 u = __builtin_bit_cast(u32, f);
  u = u + 0x7FFFu + ((u >> 16) & 1u);
  return (u16)(u >> 16);
}
__device__ inline float elu1(float x){ return x > 0.f ? x : (__expf(x) - 1.f); }
// HW packed f32x2 -> bf16x2 (RNE; 1 VALU op) -- replaces 2x integer-RNE f2b
__device__ inline u32 cvtpk(float a, float b){
  u32 r;
  asm("v_cvt_pk_bf16_f32 %0, %1, %2" : "=v"(r) : "v"(a), "v"(b));
  return r;
}

// ---- frag-major weight conversion (identical to R10/R11) ----
__global__ __launch_bounds__(256) void convert_weights(
    const float* __restrict__ sw, const float* __restrict__ crw, const float* __restrict__ cw1,
    const float* __restrict__ cw2, const float* __restrict__ trw, const float* __restrict__ tw1,
    const float* __restrict__ tw2, u16* __restrict__ ws){
  int i = blockIdx.x * 256 + threadIdx.x;
  if (i >= WS_WELE) return;
  int e = i & 511;
  int lane = e >> 3, j = e & 7, lr = lane & 15, lg = lane >> 4;
  float v;
  if (i < CRW_F){        int fs = i >> 9;              int n = (fs & 15) * 16 + lr, k = (fs >> 4) * 32 + lg * 8 + j; v = sw[n * 512 + k]; }
  else if (i < CW1_F){   int fs = (i - CRW_F) >> 9;    int n = (fs & 15) * 16 + lr, k = (fs >> 4) * 32 + lg * 8 + j; v = crw[n * 256 + k]; }
  else if (i < CW2_F){   int fs = (i - CW1_F) >> 9;    int n = (fs & 15) * 16 + lr, k = (fs >> 4) * 32 + lg * 8 + j; v = cw1[n * 256 + k]; }
  else if (i < TRW_F){   int fs = (i - CW2_F) >> 9;    int k = fs * 32 + lg * 8 + j; v = (lr < NPER) ? cw2[lr * 256 + k] : 0.f; }
  else if (i < TW1_F){   int fs = (i - TRW_F) >> 9;    int n = (fs & 15) * 16 + lr, k = (fs >> 4) * 32 + lg * 8 + j; v = trw[n * 256 + k]; }
  else if (i < TW2_F){   int fs = (i - TW1_F) >> 9;    int n = (fs & 15) * 16 + lr, k = (fs >> 4) * 32 + lg * 8 + j; v = tw1[n * 256 + k]; }
  else {                 int fs = (i - TW2_F) >> 9;    int k = fs * 32 + lg * 8 + j; v = (lr < NPER) ? tw2[lr * 256 + k] : 0.f; }
  ws[i] = f2b(v);
}

__global__ __launch_bounds__(256) void convert_h(
    const float* __restrict__ h, u16* __restrict__ h16, int n8){
  int i = blockIdx.x * 256 + threadIdx.x;
  if (i >= n8) return;
  const float4* src = (const float4*)(h + (size_t)i * 8);
  float4 q0 = src[0], q1 = src[1];
  short8 v;
  v[0]=(short)f2b(q0.x); v[1]=(short)f2b(q0.y); v[2]=(short)f2b(q0.z); v[3]=(short)f2b(q0.w);
  v[4]=(short)f2b(q1.x); v[5]=(short)f2b(q1.y); v[6]=(short)f2b(q1.z); v[7]=(short)f2b(q1.w);
  *(short8*)(h16 + (size_t)i * 8) = v;
}

// ---- in-kernel macros (identical to R11 except cvtpk in fallback) ----
#define WF(D_, BASE_, FS_) { D_ = ((const short8*)(ws + (BASE_) + (size_t)(FS_) * 512))[lane]; }
#define WF4(D_, BASE_, KS_) { WF(D_##0, BASE_, (KS_)*16 + fq + 0); WF(D_##1, BASE_, (KS_)*16 + fq + 1); \
                              WF(D_##2, BASE_, (KS_)*16 + fq + 2); WF(D_##3, BASE_, (KS_)*16 + fq + 3); }
#define LDA4(D_, SRC_, RS_, KB_) { const int ao_ = ((KB_) + lg * 16) ^ aswz; \
  _Pragma("unroll") for (int af_ = 0; af_ < 4; ++af_){ \
    const int r_ = af_ * 16 + lr; \
    D_[af_] = *(const short8*)((SRC_) + r_ * (RS_) + ao_); } }
#define GEMM16(W_, A_) { __builtin_amdgcn_s_setprio(1); \
  _Pragma("unroll") for (int af_ = 0; af_ < 4; ++af_){ \
    acc[0][af_] = __builtin_amdgcn_mfma_f32_16x16x32_bf16(W_##0, A_[af_], acc[0][af_], 0, 0, 0); \
    acc[1][af_] = __builtin_amdgcn_mfma_f32_16x16x32_bf16(W_##1, A_[af_], acc[1][af_], 0, 0, 0); \
    acc[2][af_] = __builtin_amdgcn_mfma_f32_16x16x32_bf16(W_##2, A_[af_], acc[2][af_], 0, 0, 0); \
    acc[3][af_] = __builtin_amdgcn_mfma_f32_16x16x32_bf16(W_##3, A_[af_], acc[3][af_], 0, 0, 0); } \
  __builtin_amdgcn_s_setprio(0); }
#define ZERO_ACC() { _Pragma("unroll") for (int i_ = 0; i_ < 4; ++i_) \
  _Pragma("unroll") for (int j_ = 0; j_ < 4; ++j_) acc[i_][j_] = (f32x4){0.f,0.f,0.f,0.f}; }
#define BAR() { asm volatile("s_waitcnt lgkmcnt(0)" ::: "memory"); \
  __builtin_amdgcn_sched_barrier(0); \
  __builtin_amdgcn_s_barrier(); \
  __builtin_amdgcn_sched_barrier(0); }
#define LOADC(c) { const int c_ = (c); \
  int nd_ = ((c_>>1)==0)?idx4.x:((c_>>1)==1)?idx4.y:((c_>>1)==2)?idx4.z:idx4.w; \
  const size_t o_ = (size_t)nd_ * 128 + (c_ & 1) * 64 + sq * 16; \
  if (H16){ rgA = *(const short8*)(h16 + o_); rgB = *(const short8*)(h16 + o_ + 8); } \
  else { float4 qa_=*(const float4*)(h+o_), qb_=*(const float4*)(h+o_+4); \
         float4 qc_=*(const float4*)(h+o_+8), qd_=*(const float4*)(h+o_+12); \
    u32 tA_[4] = { cvtpk(qa_.x,qa_.y), cvtpk(qa_.z,qa_.w), cvtpk(qb_.x,qb_.y), cvtpk(qb_.z,qb_.w) }; \
    u32 tB_[4] = { cvtpk(qc_.x,qc_.y), cvtpk(qc_.z,qc_.w), cvtpk(qd_.x,qd_.y), cvtpk(qd_.z,qd_.w) }; \
    rgA = *(short8*)tA_; rgB = *(short8*)tB_; } }
#define STOREC(c) { char* b_ = Zb + (((c) & 1) << 13) + srow * 128; const int sw_ = (srow & 7) << 4; \
  *(short8*)(b_ + ((sq * 32) ^ sw_))      = rgA; \
  *(short8*)(b_ + ((sq * 32 + 16) ^ sw_)) = rgB; }
#define LAYER256(WBASE_, AB_) { \
  WF4(wfA, WBASE_, 0); \
  LDA4(afA, AB_, 512, 0); \
  _Pragma("unroll") for (int ks_ = 0; ks_ < 8; ++ks_){ \
    if (ks_ & 1){ \
      if (ks_ < 7){ WF4(wfA, WBASE_, ks_ + 1); LDA4(afA, AB_, 512, (ks_ + 1) * 64); } \
      GEMM16(wfB, afB); \
    } else { \
      WF4(wfB, WBASE_, ks_ + 1); LDA4(afB, AB_, 512, (ks_ + 1) * 64); \
      GEMM16(wfA, afA); \
    } } }

template<bool H16>
__global__ __launch_bounds__(256) void torsion_kernel(
    const float* __restrict__ h, const u16* __restrict__ h16,
    const int* __restrict__ idxs, const float* __restrict__ sb,
    const float* __restrict__ c_rb, const float* __restrict__ c_b1, const float* __restrict__ c_b2,
    const float* __restrict__ t_rb, const float* __restrict__ t_b1, const float* __restrict__ t_b2,
    const u16* __restrict__ ws, float* __restrict__ out, int NT)
{
  __shared__ __attribute__((aligned(16))) char Xb[32768];   // [64][256] bf16 swizzled
  __shared__ __attribute__((aligned(16))) char Zb[32768];   // gather dbuf 2x8KB, then Y/V

  const int tid = threadIdx.x, blk = blockIdx.x;
  const int lane = tid & 63, lr = lane & 15, lg = lane >> 4;
  const int wv = tid >> 6;                     // wave 0..3 = col quarter
  const int fq = wv * 4;
  const int aswz = (lr & 7) << 4;

  const int srow = tid >> 2, sq = tid & 3;
  const int sgrow = blk * 64 + srow;
  int4 idx4 = (sgrow < NT) ? ((const int4*)idxs)[sgrow] : (int4){0, 0, 0, 0};
  short8 rgA, rgB;
  short8 wfA0, wfA1, wfA2, wfA3, wfB0, wfB1, wfB2, wfB3;
  short8 afA[4], afB[4];

  f32x4 acc[4][4];
  ZERO_ACC();

  // ---- prologue ----
  LOADC(0); STOREC(0);
  WF4(wfA, SA_F, 0);
  BAR();
  LDA4(afA, Zb, 128, 0);

  // ================ stage A: x = elu(concat(h[idx]) @ sw.T + sb); 8 chunks ================
  u32x2 xp[4][4];                              // packed residual X (this wave's D-positions)
  #pragma unroll
  for (int c = 0; c < 8; ++c){
    const char* cb = Zb + ((c & 1) << 13);
    if (c < 7) LOADC(c + 1);
    WF4(wfB, SA_F, 2 * c + 1);
    LDA4(afB, cb, 128, 64);
    GEMM16(wfA, afA);
    if (c < 7) WF4(wfA, SA_F, 2 * c + 2);
    GEMM16(wfB, afB);
    if (c < 7) STOREC(c + 1);
    if (c == 7){
      // X epilogue: elu + bias -> regs (xp) + Xb (swizzled bf16)
      #pragma unroll
      for (int wf = 0; wf < 4; ++wf){
        const int col0 = wv * 64 + wf * 16 + lg * 4;
        const float4 bb = *(const float4*)(sb + col0);
        #pragma unroll
        for (int af = 0; af < 4; ++af){
          const int row = af * 16 + lr;
          u32x2 pk = { cvtpk(elu1(acc[wf][af][0] + bb.x), elu1(acc[wf][af][1] + bb.y)),
                       cvtpk(elu1(acc[wf][af][2] + bb.z), elu1(acc[wf][af][3] + bb.w)) };
          xp[wf][af] = pk;
          *(u32x2*)(Xb + row * 512 + ((col0 * 2) ^ ((row & 7) << 4))) = pk;
        }
      }
    }
    BAR();
    if (c < 7) LDA4(afA, Zb + (((c + 1) & 1) << 13), 128, 0);
  }

  // ================ heads: c (score) then t (coeffs) ================
  f32x4 scC = (f32x4){0,0,0,0}, scT = (f32x4){0,0,0,0};
  #pragma unroll
  for (int hd = 0; hd < 2; ++hd){
    const int RWF = hd ? TRW_F : CRW_F;
    const int W1F = hd ? TW1_F : CW1_F;
    const int W2F = hd ? TW2_F : CW2_F;
    const float* RB = hd ? t_rb : c_rb;
    const float* B1 = hd ? t_b1 : c_b1;
    const float* B2 = hd ? t_b2 : c_b2;

    // ---- y = x + elu(x @ rw.T + rb) -> Zb  (residual from xp regs, no Xb re-read) ----
    ZERO_ACC();
    LAYER256(RWF, Xb);
    #pragma unroll
    for (int wf = 0; wf < 4; ++wf){
      const int col0 = wv * 64 + wf * 16 + lg * 4;
      const float4 bb = *(const float4*)(RB + col0);
      #pragma unroll
      for (int af = 0; af < 4; ++af){
        const int row = af * 16 + lr;
        const u32x2 xv = xp[wf][af];
        const float x0 = __builtin_bit_cast(float, xv[0] << 16);
        const float x1 = __builtin_bit_cast(float, xv[0] & 0xffff0000u);
        const float x2 = __builtin_bit_cast(float, xv[1] << 16);
        const float x3 = __builtin_bit_cast(float, xv[1] & 0xffff0000u);
        u32x2 pk = { cvtpk(x0 + elu1(acc[wf][af][0] + bb.x), x1 + elu1(acc[wf][af][1] + bb.y)),
                     cvtpk(x2 + elu1(acc[wf][af][2] + bb.z), x3 + elu1(acc[wf][af][3] + bb.w)) };
        *(u32x2*)(Zb + row * 512 + ((col0 * 2) ^ ((row & 7) << 4))) = pk;
      }
    }
    BAR();                                  // Y visible

    // ---- v = elu(y @ w1.T + b1): layer, drain-bar, V epilogue -> Zb ----
    ZERO_ACC();
    LAYER256(W1F, Zb);
    BAR();                                  // all Y reads done before overwrite
    #pragma unroll
    for (int wf = 0; wf < 4; ++wf){
      const int col0 = wv * 64 + wf * 16 + lg * 4;
      const float4 bb = *(const float4*)(B1 + col0);
      #pragma unroll
      for (int af = 0; af < 4; ++af){
        const int row = af * 16 + lr;
        u32x2 pk = { cvtpk(elu1(acc[wf][af][0] + bb.x), elu1(acc[wf][af][1] + bb.y)),
                     cvtpk(elu1(acc[wf][af][2] + bb.z), elu1(acc[wf][af][3] + bb.w)) };
        *(u32x2*)(Zb + row * 512 + ((col0 * 2) ^ ((row & 7) << 4))) = pk;
      }
    }
    BAR();                                  // V visible

    // ---- out16 = v @ w2p.T: wave wv owns rows wv*16..+15 ----
    {
      f32x4 a1 = (f32x4){0, 0, 0, 0};
      const int vr = wv * 16 + lr;
      const int vswz = (vr & 7) << 4;
      __builtin_amdgcn_s_setprio(1);
      #pragma unroll
      for (int kt = 0; kt < 8; ++kt){
        short8 aw; WF(aw, W2F, kt);
        short8 bv = *(const short8*)(Zb + vr * 512 + ((kt * 64 + lg * 16) ^ vswz));
        a1 = __builtin_amdgcn_mfma_f32_16x16x32_bf16(aw, bv, a1, 0, 0, 0);
      }
      __builtin_amdgcn_s_setprio(0);
      #pragma unroll
      for (int r = 0; r < 4; ++r){
        const int nn = lg * 4 + r;
        a1[r] += (nn < NPER) ? B2[nn] : 0.f;
      }
      if (hd == 0) scC = a1; else scT = a1;
      BAR();                                // w2's V reads done before head t's Y overwrites
    }
  }

  // ---- epilogue: score & coeff for row (wv*16+lr) live in this lane ----
  const int grow = blk * 64 + wv * 16 + lr;
  if (grow < NT){
    #pragma unroll
    for (int r = 0; r < 4; ++r){
      const int nn = lg * 4 + r;
      if (nn < NPER){
        const float s = scC[r], c = scT[r];
        out[(size_t)grow * 6 + nn] = s;
        out[(size_t)NT * 6 + (size_t)grow * 6 + nn] = c * 1e-3f * (1.f / (1.f + __expf(-s)));
      }
    }
  }
}

extern "C" void kernel_launch(void* const* d_in, const int* in_sizes, int n_in,
                              void* d_out, int out_size, void* d_ws, size_t ws_size,
                              hipStream_t stream){
  const float* h    = (const float*)d_in[0];
  const int*   idxs = (const int*)d_in[1];
  const float* sw   = (const float*)d_in[2];
  const float* sb   = (const float*)d_in[3];
  const float* trw  = (const float*)d_in[4];
  const float* trb  = (const float*)d_in[5];
  const float* tw1  = (const float*)d_in[6];
  const float* tb1  = (const float*)d_in[7];
  const float* tw2  = (const float*)d_in[8];
  const float* tb2  = (const float*)d_in[9];
  const float* crw  = (const float*)d_in[10];
  const float* crb  = (const float*)d_in[11];
  const float* cw1  = (const float*)d_in[12];
  const float* cb1  = (const float*)d_in[13];
  const float* cw2  = (const float*)d_in[14];
  const float* cb2  = (const float*)d_in[15];
  u16* ws    = (u16*)d_ws;
  float* out = (float*)d_out;
  const int NT = in_sizes[1] / 4;
  const int nh = in_sizes[0];
  const bool useH16 = ws_size >= (size_t)(WS_WELE + nh) * 2;

  hipLaunchKernelGGL(convert_weights, dim3((WS_WELE + 255) / 256), dim3(256), 0, stream,
                     sw, crw, cw1, cw2, trw, tw1, tw2, ws);
  u16* h16 = ws + WS_WELE;
  const int nblk = (NT + 63) / 64;
  if (useH16){
    const int n8 = nh / 8;
    hipLaunchKernelGGL(convert_h, dim3((n8 + 255) / 256), dim3(256), 0, stream, h, h16, n8);
    torsion_kernel<true><<<dim3(nblk), dim3(256), 0, stream>>>(
        h, h16, idxs, sb, crb, cb1, cb2, trb, tb1, tb2, ws, out, NT);
  } else {
    torsion_kernel<false><<<dim3(nblk), dim3(256), 0, stream>>>(
        h, h16, idxs, sb, crb, cb1, cb2, trb, tb1, tb2, ws, out, NT);
  }
}

// Round 14
// 483.440 us; speedup vs baseline: 1.4295x; 1.4295x over previous
//
#include <hip/hip_runtime.h>
#include <stdint.h>

typedef __attribute__((ext_vector_type(8))) short short8;
typedef __attribute__((ext_vector_type(4))) float f32x4;
typedef __attribute__((ext_vector_type(2))) unsigned int u32x2;
typedef unsigned short u16;
typedef unsigned int u32;

#define NPER 6
// frag-major weight regions (bf16 element offsets). Each frag = 512 elems = 1KB,
// lane-major: frag[lane][j] = W[n(frag,lane)][k(frag,lane,j)].   (identical to R10/R11)
#define SA_F   0
#define CRW_F  131072
#define CW1_F  196608
#define CW2_F  262144
#define TRW_F  266240
#define TW1_F  331776
#define TW2_F  397312
#define WS_WELE 401408   // h16 follows

__device__ inline u16 f2b(float f){                 // f32 -> bf16 (RNE) -- converter kernels only
  u32 u = __builtin_bit_cast(u32, f);
  u = u + 0x7FFFu + ((u >> 16) & 1u);
  return (u16)(u >> 16);
}
__device__ inline float elu1(float x){ return x > 0.f ? x : (__expf(x) - 1.f); }
// HW packed f32x2 -> bf16x2 (RNE; 1 VALU op; bit-identical to f2b -- verified R13 absmax)
__device__ inline u32 cvtpk(float a, float b){
  u32 r;
  asm("v_cvt_pk_bf16_f32 %0, %1, %2" : "=v"(r) : "v"(a), "v"(b));
  return r;
}

// ---- frag-major weight conversion (identical to R10/R11) ----
__global__ __launch_bounds__(256) void convert_weights(
    const float* __restrict__ sw, const float* __restrict__ crw, const float* __restrict__ cw1,
    const float* __restrict__ cw2, const float* __restrict__ trw, const float* __restrict__ tw1,
    const float* __restrict__ tw2, u16* __restrict__ ws){
  int i = blockIdx.x * 256 + threadIdx.x;
  if (i >= WS_WELE) return;
  int e = i & 511;
  int lane = e >> 3, j = e & 7, lr = lane & 15, lg = lane >> 4;
  float v;
  if (i < CRW_F){        int fs = i >> 9;              int n = (fs & 15) * 16 + lr, k = (fs >> 4) * 32 + lg * 8 + j; v = sw[n * 512 + k]; }
  else if (i < CW1_F){   int fs = (i - CRW_F) >> 9;    int n = (fs & 15) * 16 + lr, k = (fs >> 4) * 32 + lg * 8 + j; v = crw[n * 256 + k]; }
  else if (i < CW2_F){   int fs = (i - CW1_F) >> 9;    int n = (fs & 15) * 16 + lr, k = (fs >> 4) * 32 + lg * 8 + j; v = cw1[n * 256 + k]; }
  else if (i < TRW_F){   int fs = (i - CW2_F) >> 9;    int k = fs * 32 + lg * 8 + j; v = (lr < NPER) ? cw2[lr * 256 + k] : 0.f; }
  else if (i < TW1_F){   int fs = (i - TRW_F) >> 9;    int n = (fs & 15) * 16 + lr, k = (fs >> 4) * 32 + lg * 8 + j; v = trw[n * 256 + k]; }
  else if (i < TW2_F){   int fs = (i - TW1_F) >> 9;    int n = (fs & 15) * 16 + lr, k = (fs >> 4) * 32 + lg * 8 + j; v = tw1[n * 256 + k]; }
  else {                 int fs = (i - TW2_F) >> 9;    int k = fs * 32 + lg * 8 + j; v = (lr < NPER) ? tw2[lr * 256 + k] : 0.f; }
  ws[i] = f2b(v);
}

__global__ __launch_bounds__(256) void convert_h(
    const float* __restrict__ h, u16* __restrict__ h16, int n8){
  int i = blockIdx.x * 256 + threadIdx.x;
  if (i >= n8) return;
  const float4* src = (const float4*)(h + (size_t)i * 8);
  float4 q0 = src[0], q1 = src[1];
  short8 v;
  v[0]=(short)f2b(q0.x); v[1]=(short)f2b(q0.y); v[2]=(short)f2b(q0.z); v[3]=(short)f2b(q0.w);
  v[4]=(short)f2b(q1.x); v[5]=(short)f2b(q1.y); v[6]=(short)f2b(q1.z); v[7]=(short)f2b(q1.w);
  *(short8*)(h16 + (size_t)i * 8) = v;
}

// ---- in-kernel macros (identical to R11; cvtpk in fallback) ----
#define WF(D_, BASE_, FS_) { D_ = ((const short8*)(ws + (BASE_) + (size_t)(FS_) * 512))[lane]; }
#define WF4(D_, BASE_, KS_) { WF(D_##0, BASE_, (KS_)*16 + fq + 0); WF(D_##1, BASE_, (KS_)*16 + fq + 1); \
                              WF(D_##2, BASE_, (KS_)*16 + fq + 2); WF(D_##3, BASE_, (KS_)*16 + fq + 3); }
#define LDA4(D_, SRC_, RS_, KB_) { const int ao_ = ((KB_) + lg * 16) ^ aswz; \
  _Pragma("unroll") for (int af_ = 0; af_ < 4; ++af_){ \
    const int r_ = af_ * 16 + lr; \
    D_[af_] = *(const short8*)((SRC_) + r_ * (RS_) + ao_); } }
#define GEMM16(W_, A_) { __builtin_amdgcn_s_setprio(1); \
  _Pragma("unroll") for (int af_ = 0; af_ < 4; ++af_){ \
    acc[0][af_] = __builtin_amdgcn_mfma_f32_16x16x32_bf16(W_##0, A_[af_], acc[0][af_], 0, 0, 0); \
    acc[1][af_] = __builtin_amdgcn_mfma_f32_16x16x32_bf16(W_##1, A_[af_], acc[1][af_], 0, 0, 0); \
    acc[2][af_] = __builtin_amdgcn_mfma_f32_16x16x32_bf16(W_##2, A_[af_], acc[2][af_], 0, 0, 0); \
    acc[3][af_] = __builtin_amdgcn_mfma_f32_16x16x32_bf16(W_##3, A_[af_], acc[3][af_], 0, 0, 0); } \
  __builtin_amdgcn_s_setprio(0); }
#define ZERO_ACC() { _Pragma("unroll") for (int i_ = 0; i_ < 4; ++i_) \
  _Pragma("unroll") for (int j_ = 0; j_ < 4; ++j_) acc[i_][j_] = (f32x4){0.f,0.f,0.f,0.f}; }
#define BAR() { asm volatile("s_waitcnt lgkmcnt(0)" ::: "memory"); \
  __builtin_amdgcn_sched_barrier(0); \
  __builtin_amdgcn_s_barrier(); \
  __builtin_amdgcn_sched_barrier(0); }
#define LOADC(c) { const int c_ = (c); \
  int nd_ = ((c_>>1)==0)?idx4.x:((c_>>1)==1)?idx4.y:((c_>>1)==2)?idx4.z:idx4.w; \
  const size_t o_ = (size_t)nd_ * 128 + (c_ & 1) * 64 + sq * 16; \
  if (H16){ rgA = *(const short8*)(h16 + o_); rgB = *(const short8*)(h16 + o_ + 8); } \
  else { float4 qa_=*(const float4*)(h+o_), qb_=*(const float4*)(h+o_+4); \
         float4 qc_=*(const float4*)(h+o_+8), qd_=*(const float4*)(h+o_+12); \
    u32 tA_[4] = { cvtpk(qa_.x,qa_.y), cvtpk(qa_.z,qa_.w), cvtpk(qb_.x,qb_.y), cvtpk(qb_.z,qb_.w) }; \
    u32 tB_[4] = { cvtpk(qc_.x,qc_.y), cvtpk(qc_.z,qc_.w), cvtpk(qd_.x,qd_.y), cvtpk(qd_.z,qd_.w) }; \
    rgA = *(short8*)tA_; rgB = *(short8*)tB_; } }
#define STOREC(c) { char* b_ = Zb + (((c) & 1) << 13) + srow * 128; const int sw_ = (srow & 7) << 4; \
  *(short8*)(b_ + ((sq * 32) ^ sw_))      = rgA; \
  *(short8*)(b_ + ((sq * 32 + 16) ^ sw_)) = rgB; }
#define LAYER256(WBASE_, AB_) { \
  WF4(wfA, WBASE_, 0); \
  LDA4(afA, AB_, 512, 0); \
  _Pragma("unroll") for (int ks_ = 0; ks_ < 8; ++ks_){ \
    if (ks_ & 1){ \
      if (ks_ < 7){ WF4(wfA, WBASE_, ks_ + 1); LDA4(afA, AB_, 512, (ks_ + 1) * 64); } \
      GEMM16(wfB, afB); \
    } else { \
      WF4(wfB, WBASE_, ks_ + 1); LDA4(afB, AB_, 512, (ks_ + 1) * 64); \
      GEMM16(wfA, afA); \
    } } }

template<bool H16>
__global__ __launch_bounds__(256) void torsion_kernel(
    const float* __restrict__ h, const u16* __restrict__ h16,
    const int* __restrict__ idxs, const float* __restrict__ sb,
    const float* __restrict__ c_rb, const float* __restrict__ c_b1, const float* __restrict__ c_b2,
    const float* __restrict__ t_rb, const float* __restrict__ t_b1, const float* __restrict__ t_b2,
    const u16* __restrict__ ws, float* __restrict__ out, int NT)
{
  __shared__ __attribute__((aligned(16))) char Xb[32768];   // [64][256] bf16 swizzled
  __shared__ __attribute__((aligned(16))) char Zb[32768];   // gather dbuf 2x8KB, then Y/V

  const int tid = threadIdx.x, blk = blockIdx.x;
  const int lane = tid & 63, lr = lane & 15, lg = lane >> 4;
  const int wv = tid >> 6;                     // wave 0..3 = col quarter
  const int fq = wv * 4;
  const int aswz = (lr & 7) << 4;

  const int srow = tid >> 2, sq = tid & 3;
  const int sgrow = blk * 64 + srow;
  int4 idx4 = (sgrow < NT) ? ((const int4*)idxs)[sgrow] : (int4){0, 0, 0, 0};
  short8 rgA, rgB;
  short8 wfA0, wfA1, wfA2, wfA3, wfB0, wfB1, wfB2, wfB3;
  short8 afA[4], afB[4];

  f32x4 acc[4][4];
  ZERO_ACC();

  // ---- prologue ----
  LOADC(0); STOREC(0);
  WF4(wfA, SA_F, 0);
  BAR();
  LDA4(afA, Zb, 128, 0);

  // ================ stage A: x = elu(concat(h[idx]) @ sw.T + sb); 8 chunks ================
  #pragma unroll
  for (int c = 0; c < 8; ++c){
    const char* cb = Zb + ((c & 1) << 13);
    if (c < 7) LOADC(c + 1);
    WF4(wfB, SA_F, 2 * c + 1);
    LDA4(afB, cb, 128, 64);
    GEMM16(wfA, afA);
    if (c < 7) WF4(wfA, SA_F, 2 * c + 2);
    GEMM16(wfB, afB);
    if (c < 7) STOREC(c + 1);
    if (c == 7){
      // X epilogue: elu + bias -> Xb (swizzled bf16)
      #pragma unroll
      for (int wf = 0; wf < 4; ++wf){
        const int col0 = wv * 64 + wf * 16 + lg * 4;
        const float4 bb = *(const float4*)(sb + col0);
        #pragma unroll
        for (int af = 0; af < 4; ++af){
          const int row = af * 16 + lr;
          u32x2 pk = { cvtpk(elu1(acc[wf][af][0] + bb.x), elu1(acc[wf][af][1] + bb.y)),
                       cvtpk(elu1(acc[wf][af][2] + bb.z), elu1(acc[wf][af][3] + bb.w)) };
          *(u32x2*)(Xb + row * 512 + ((col0 * 2) ^ ((row & 7) << 4))) = pk;
        }
      }
    }
    BAR();
    if (c < 7) LDA4(afA, Zb + (((c + 1) & 1) << 13), 128, 0);
  }

  // ================ heads: c (score) then t (coeffs) ================
  f32x4 scC = (f32x4){0,0,0,0}, scT = (f32x4){0,0,0,0};
  #pragma unroll
  for (int hd = 0; hd < 2; ++hd){
    const int RWF = hd ? TRW_F : CRW_F;
    const int W1F = hd ? TW1_F : CW1_F;
    const int W2F = hd ? TW2_F : CW2_F;
    const float* RB = hd ? t_rb : c_rb;
    const float* B1 = hd ? t_b1 : c_b1;
    const float* B2 = hd ? t_b2 : c_b2;

    // ---- y = x + elu(x @ rw.T + rb) -> Zb  (residual re-read from Xb) ----
    ZERO_ACC();
    LAYER256(RWF, Xb);
    #pragma unroll
    for (int wf = 0; wf < 4; ++wf){
      const int col0 = wv * 64 + wf * 16 + lg * 4;
      const float4 bb = *(const float4*)(RB + col0);
      #pragma unroll
      for (int af = 0; af < 4; ++af){
        const int row = af * 16 + lr;
        const int boff = (col0 * 2) ^ ((row & 7) << 4);
        u32x2 xv = *(const u32x2*)(Xb + row * 512 + boff);
        const float x0 = __builtin_bit_cast(float, xv[0] << 16);
        const float x1 = __builtin_bit_cast(float, xv[0] & 0xffff0000u);
        const float x2 = __builtin_bit_cast(float, xv[1] << 16);
        const float x3 = __builtin_bit_cast(float, xv[1] & 0xffff0000u);
        u32x2 pk = { cvtpk(x0 + elu1(acc[wf][af][0] + bb.x), x1 + elu1(acc[wf][af][1] + bb.y)),
                     cvtpk(x2 + elu1(acc[wf][af][2] + bb.z), x3 + elu1(acc[wf][af][3] + bb.w)) };
        *(u32x2*)(Zb + row * 512 + boff) = pk;
      }
    }
    BAR();                                  // Y visible

    // ---- v = elu(y @ w1.T + b1): layer, drain-bar, V epilogue -> Zb ----
    ZERO_ACC();
    LAYER256(W1F, Zb);
    BAR();                                  // all Y reads done before overwrite
    #pragma unroll
    for (int wf = 0; wf < 4; ++wf){
      const int col0 = wv * 64 + wf * 16 + lg * 4;
      const float4 bb = *(const float4*)(B1 + col0);
      #pragma unroll
      for (int af = 0; af < 4; ++af){
        const int row = af * 16 + lr;
        u32x2 pk = { cvtpk(elu1(acc[wf][af][0] + bb.x), elu1(acc[wf][af][1] + bb.y)),
                     cvtpk(elu1(acc[wf][af][2] + bb.z), elu1(acc[wf][af][3] + bb.w)) };
        *(u32x2*)(Zb + row * 512 + ((col0 * 2) ^ ((row & 7) << 4))) = pk;
      }
    }
    BAR();                                  // V visible

    // ---- out16 = v @ w2p.T: wave wv owns rows wv*16..+15 ----
    {
      f32x4 a1 = (f32x4){0, 0, 0, 0};
      const int vr = wv * 16 + lr;
      const int vswz = (vr & 7) << 4;
      __builtin_amdgcn_s_setprio(1);
      #pragma unroll
      for (int kt = 0; kt < 8; ++kt){
        short8 aw; WF(aw, W2F, kt);
        short8 bv = *(const short8*)(Zb + vr * 512 + ((kt * 64 + lg * 16) ^ vswz));
        a1 = __builtin_amdgcn_mfma_f32_16x16x32_bf16(aw, bv, a1, 0, 0, 0);
      }
      __builtin_amdgcn_s_setprio(0);
      #pragma unroll
      for (int r = 0; r < 4; ++r){
        const int nn = lg * 4 + r;
        a1[r] += (nn < NPER) ? B2[nn] : 0.f;
      }
      if (hd == 0) scC = a1; else scT = a1;
      BAR();                                // w2's V reads done before head t's Y overwrites
    }
  }

  // ---- epilogue: score & coeff for row (wv*16+lr) live in this lane ----
  const int grow = blk * 64 + wv * 16 + lr;
  if (grow < NT){
    #pragma unroll
    for (int r = 0; r < 4; ++r){
      const int nn = lg * 4 + r;
      if (nn < NPER){
        const float s = scC[r], c = scT[r];
        out[(size_t)grow * 6 + nn] = s;
        out[(size_t)NT * 6 + (size_t)grow * 6 + nn] = c * 1e-3f * (1.f / (1.f + __expf(-s)));
      }
    }
  }
}

extern "C" void kernel_launch(void* const* d_in, const int* in_sizes, int n_in,
                              void* d_out, int out_size, void* d_ws, size_t ws_size,
                              hipStream_t stream){
  const float* h    = (const float*)d_in[0];
  const int*   idxs = (const int*)d_in[1];
  const float* sw   = (const float*)d_in[2];
  const float* sb   = (const float*)d_in[3];
  const float* trw  = (const float*)d_in[4];
  const float* trb  = (const float*)d_in[5];
  const float* tw1  = (const float*)d_in[6];
  const float* tb1  = (const float*)d_in[7];
  const float* tw2  = (const float*)d_in[8];
  const float* tb2  = (const float*)d_in[9];
  const float* crw  = (const float*)d_in[10];
  const float* crb  = (const float*)d_in[11];
  const float* cw1  = (const float*)d_in[12];
  const float* cb1  = (const float*)d_in[13];
  const float* cw2  = (const float*)d_in[14];
  const float* cb2  = (const float*)d_in[15];
  u16* ws    = (u16*)d_ws;
  float* out = (float*)d_out;
  const int NT = in_sizes[1] / 4;
  const int nh = in_sizes[0];
  const bool useH16 = ws_size >= (size_t)(WS_WELE + nh) * 2;

  hipLaunchKernelGGL(convert_weights, dim3((WS_WELE + 255) / 256), dim3(256), 0, stream,
                     sw, crw, cw1, cw2, trw, tw1, tw2, ws);
  u16* h16 = ws + WS_WELE;
  const int nblk = (NT + 63) / 64;
  if (useH16){
    const int n8 = nh / 8;
    hipLaunchKernelGGL(convert_h, dim3((n8 + 255) / 256), dim3(256), 0, stream, h, h16, n8);
    torsion_kernel<true><<<dim3(nblk), dim3(256), 0, stream>>>(
        h, h16, idxs, sb, crb, cb1, cb2, trb, tb1, tb2, ws, out, NT);
  } else {
    torsion_kernel<false><<<dim3(nblk), dim3(256), 0, stream>>>(
        h, h16, idxs, sb, crb, cb1, cb2, trb, tb1, tb2, ws, out, NT);
  }
}